// Round 1
// baseline (1111.656 us; speedup 1.0000x reference)
//
#include <hip/hip_runtime.h>
#include <hip/hip_bf16.h>
#include <cstdint>
#include <cstddef>

#define T_DIM 8
#define N_NODES 50000
#define F_DIM 64
#define H_DIM 32
#define L_DIM 64
#define E_EDGES 800000

__device__ __forceinline__ unsigned short f2bf(float f) {
  unsigned u = __float_as_uint(f);
  u = u + 0x7FFFu + ((u >> 16) & 1u);   // round-to-nearest-even
  return (unsigned short)(u >> 16);
}
__device__ __forceinline__ float bf2f(unsigned short b) {
  return __uint_as_float(((unsigned)b) << 16);
}

// K1: deg[t][dst] counts (self-loop added later as +1)
__global__ void k_count(const int* __restrict__ ei, int* __restrict__ deg) {
  int idx = blockIdx.x * 256 + threadIdx.x;
  if (idx >= T_DIM * E_EDGES) return;
  int t = idx / E_EDGES;
  int e = idx - t * E_EDGES;
  int dst = ei[(t * 2 + 1) * E_EDGES + e];
  atomicAdd(&deg[t * N_NODES + dst], 1);
}

// K2: per-t exclusive prefix sum of deg -> row_ptr, cursor (copy). 1024 threads/block, 1 block per t.
__global__ void k_scan(const int* __restrict__ deg, int* __restrict__ row_ptr,
                       int* __restrict__ cursor) {
  int t = blockIdx.x;
  const int* d = deg + t * N_NODES;
  int* rp = row_ptr + (size_t)t * (N_NODES + 1);
  int* cur = cursor + t * N_NODES;
  __shared__ int wsum[16];
  __shared__ int chunk_total_sh;
  int tid = threadIdx.x;
  int lane = tid & 63, wid = tid >> 6;
  int carry = 0;
  for (int base = 0; base < N_NODES; base += 4096) {
    int i0 = base + tid * 4;
    int v0 = (i0 + 0 < N_NODES) ? d[i0 + 0] : 0;
    int v1 = (i0 + 1 < N_NODES) ? d[i0 + 1] : 0;
    int v2 = (i0 + 2 < N_NODES) ? d[i0 + 2] : 0;
    int v3 = (i0 + 3 < N_NODES) ? d[i0 + 3] : 0;
    int tsum = v0 + v1 + v2 + v3;
    // inclusive wave scan of tsum
    int sc = tsum;
    #pragma unroll
    for (int off = 1; off < 64; off <<= 1) {
      int o = __shfl_up(sc, off, 64);
      if (lane >= off) sc += o;
    }
    if (lane == 63) wsum[wid] = sc;
    __syncthreads();
    if (wid == 0) {
      int wv = (lane < 16) ? wsum[lane] : 0;
      int ws = wv;
      #pragma unroll
      for (int off = 1; off < 16; off <<= 1) {
        int o = __shfl_up(ws, off, 64);
        if (lane >= off) ws += o;
      }
      if (lane < 16) wsum[lane] = ws - wv;  // exclusive wave offset
      if (lane == 15) chunk_total_sh = ws;
    }
    __syncthreads();
    int excl = carry + wsum[wid] + (sc - tsum);
    if (i0 + 0 < N_NODES) { rp[i0 + 0] = excl;                cur[i0 + 0] = excl; }
    if (i0 + 1 < N_NODES) { rp[i0 + 1] = excl + v0;           cur[i0 + 1] = excl + v0; }
    if (i0 + 2 < N_NODES) { rp[i0 + 2] = excl + v0 + v1;      cur[i0 + 2] = excl + v0 + v1; }
    if (i0 + 3 < N_NODES) { rp[i0 + 3] = excl + v0 + v1 + v2; cur[i0 + 3] = excl + v0 + v1 + v2; }
    carry += chunk_total_sh;
    __syncthreads();
  }
  if (tid == 0) rp[N_NODES] = carry;  // == E_EDGES
}

// K3: fill CSR column (src) lists using atomic cursors
__global__ void k_fill(const int* __restrict__ ei, int* __restrict__ cursor,
                       int* __restrict__ csr) {
  int idx = blockIdx.x * 256 + threadIdx.x;
  if (idx >= T_DIM * E_EDGES) return;
  int t = idx / E_EDGES;
  int e = idx - t * E_EDGES;
  int src = ei[(t * 2 + 0) * E_EDGES + e];
  int dst = ei[(t * 2 + 1) * E_EDGES + e];
  int pos = atomicAdd(&cursor[t * N_NODES + dst], 1);
  csr[(size_t)t * E_EDGES + pos] = src;
}

// K4: s[t][n][:] = rsqrt(deg+1) * (x[t][n][:] @ conv_w), stored bf16
__global__ void k_xw(const float* __restrict__ x, const float* __restrict__ w,
                     const int* __restrict__ deg, unsigned short* __restrict__ s) {
  int t = blockIdx.y;
  int n = blockIdx.x * 256 + threadIdx.x;
  if (n >= N_NODES) return;
  const float4* xr = reinterpret_cast<const float4*>(x + ((size_t)t * N_NODES + n) * F_DIM);
  const float4* w4 = reinterpret_cast<const float4*>(w);
  float4 acc[8];
  #pragma unroll
  for (int h = 0; h < 8; ++h) acc[h] = make_float4(0.f, 0.f, 0.f, 0.f);
  for (int k4 = 0; k4 < 16; ++k4) {
    float4 xv = xr[k4];
    #pragma unroll
    for (int kk = 0; kk < 4; ++kk) {
      float xs = (kk == 0) ? xv.x : (kk == 1) ? xv.y : (kk == 2) ? xv.z : xv.w;
      #pragma unroll
      for (int h = 0; h < 8; ++h) {
        float4 wv = w4[(k4 * 4 + kk) * 8 + h];   // wave-uniform -> scalar loads
        acc[h].x += xs * wv.x; acc[h].y += xs * wv.y;
        acc[h].z += xs * wv.z; acc[h].w += xs * wv.w;
      }
    }
  }
  float dinv = rsqrtf((float)(deg[t * N_NODES + n] + 1));
  unsigned short* srow = s + ((size_t)t * N_NODES + n) * H_DIM;
  #pragma unroll
  for (int h = 0; h < 8; ++h) {
    uint2 u;
    u.x = (unsigned)f2bf(acc[h].x * dinv) | ((unsigned)f2bf(acc[h].y * dinv) << 16);
    u.y = (unsigned)f2bf(acc[h].z * dinv) | ((unsigned)f2bf(acc[h].w * dinv) << 16);
    *reinterpret_cast<uint2*>(srow + h * 4) = u;
  }
}

// K5: per-node gather of s[src] over incoming edges + self, relu(dinv*sum + b), block partial pool
__global__ void k_gather(const unsigned short* __restrict__ s, const int* __restrict__ csr,
                         const int* __restrict__ row_ptr, const float* __restrict__ conv_b,
                         float* __restrict__ partials, int nblk) {
  int t = blockIdx.y;
  int tid = threadIdx.x;
  int g = tid >> 3, j = tid & 7;   // 32 node-groups x 8 lanes; lane covers 4 of 32 features
  int n = blockIdx.x * 32 + g;
  float4 val = make_float4(0.f, 0.f, 0.f, 0.f);
  if (n < N_NODES) {
    const int* rp = row_ptr + (size_t)t * (N_NODES + 1) + n;
    int start = rp[0], end = rp[1];
    float dinv = rsqrtf((float)(end - start + 1));
    const unsigned short* sbase = s + (size_t)t * N_NODES * H_DIM;
    ushort4 u = *reinterpret_cast<const ushort4*>(sbase + (size_t)n * H_DIM + j * 4);
    float4 acc = make_float4(bf2f(u.x), bf2f(u.y), bf2f(u.z), bf2f(u.w));
    const int* col = csr + (size_t)t * E_EDGES;
    for (int p = start; p < end; ++p) {
      int c = col[p];
      ushort4 v = *reinterpret_cast<const ushort4*>(sbase + (size_t)c * H_DIM + j * 4);
      acc.x += bf2f(v.x); acc.y += bf2f(v.y); acc.z += bf2f(v.z); acc.w += bf2f(v.w);
    }
    const float4 b = reinterpret_cast<const float4*>(conv_b)[j];
    val.x = fmaxf(acc.x * dinv + b.x, 0.f);
    val.y = fmaxf(acc.y * dinv + b.y, 0.f);
    val.z = fmaxf(acc.z * dinv + b.z, 0.f);
    val.w = fmaxf(acc.w * dinv + b.w, 0.f);
  }
  // reduce across the 8 groups of each wave (classes = lane&7)
  #pragma unroll
  for (int off = 8; off < 64; off <<= 1) {
    val.x += __shfl_xor(val.x, off, 64);
    val.y += __shfl_xor(val.y, off, 64);
    val.z += __shfl_xor(val.z, off, 64);
    val.w += __shfl_xor(val.w, off, 64);
  }
  __shared__ float red[4][32];
  int wid = tid >> 6, lane = tid & 63;
  if (lane < 8) {
    red[wid][lane * 4 + 0] = val.x;
    red[wid][lane * 4 + 1] = val.y;
    red[wid][lane * 4 + 2] = val.z;
    red[wid][lane * 4 + 3] = val.w;
  }
  __syncthreads();
  if (tid < 32) {
    float sum = red[0][tid] + red[1][tid] + red[2][tid] + red[3][tid];
    partials[((size_t)t * nblk + blockIdx.x) * H_DIM + tid] = sum;
  }
}

// K5b: reduce per-block partials -> pooled node-sum per (t,h)
__global__ void k_reduce(const float* __restrict__ partials, float* __restrict__ seq_raw,
                         int nblk) {
  int t = blockIdx.x;
  int tid = threadIdx.x;           // 256
  int h = tid & 31, w = tid >> 5;  // 8 slices
  float sum = 0.f;
  for (int b = w; b < nblk; b += 8) sum += partials[((size_t)t * nblk + b) * H_DIM + h];
  __shared__ float red[8][32];
  red[w][h] = sum;
  __syncthreads();
  if (tid < 32) {
    float sm = 0.f;
    #pragma unroll
    for (int i = 0; i < 8; ++i) sm += red[i][tid];
    seq_raw[t * H_DIM + tid] = sm;
  }
}

// K6a: precompute per-t x-part of LSTM gates: gx[t][g] = b_ih+b_hh + w_ih[g,:]@(seq_sum/N)
__global__ void k_gatex(const float* __restrict__ seq_raw, const float* __restrict__ w_ih,
                        const float* __restrict__ b_ih, const float* __restrict__ b_hh,
                        float* __restrict__ gx) {
  int t = blockIdx.x;
  int j = threadIdx.x;  // 256
  __shared__ float xb[32];
  if (j < 32) xb[j] = seq_raw[t * H_DIM + j] * (1.0f / (float)N_NODES);
  __syncthreads();
  float g = b_ih[j] + b_hh[j];
  #pragma unroll
  for (int k = 0; k < 32; ++k) g += w_ih[j * 32 + k] * xb[k];
  gx[t * 256 + j] = g;
}

// K6b: sequential LSTM (8 steps) + fc head. Single block.
__global__ void k_lstm(const float* __restrict__ gx, const float* __restrict__ w_hh,
                       const float* __restrict__ fc_w, const float* __restrict__ fc_b,
                       float* __restrict__ out) {
  __shared__ float hbuf[64], cbuf[64], gates[256];
  int j = threadIdx.x;  // 256
  if (j < 64) { hbuf[j] = 0.f; cbuf[j] = 0.f; }
  __syncthreads();
  for (int t = 0; t < T_DIM; ++t) {
    float g = gx[t * 256 + j];
    #pragma unroll 8
    for (int k = 0; k < 64; ++k) g += w_hh[j * 64 + k] * hbuf[k];
    gates[j] = g;
    __syncthreads();
    if (j < 64) {
      float ii = 1.f / (1.f + expf(-gates[j]));
      float ff = 1.f / (1.f + expf(-gates[64 + j]));
      float gg = tanhf(gates[128 + j]);
      float oo = 1.f / (1.f + expf(-gates[192 + j]));
      float c = ff * cbuf[j] + ii * gg;
      cbuf[j] = c;
      hbuf[j] = oo * tanhf(c);
    }
    __syncthreads();
  }
  if (j == 0) {
    float acc = 0.f;
    for (int k = 0; k < 64; ++k) acc += hbuf[k] * fc_w[k];
    out[0] = acc + fc_b[0];
  }
}

extern "C" void kernel_launch(void* const* d_in, const int* in_sizes, int n_in,
                              void* d_out, int out_size, void* d_ws, size_t ws_size,
                              hipStream_t stream) {
  const float* x      = (const float*)d_in[0];
  const int*   ei     = (const int*)  d_in[1];
  const float* conv_w = (const float*)d_in[2];
  const float* conv_b = (const float*)d_in[3];
  const float* w_ih   = (const float*)d_in[4];
  const float* w_hh   = (const float*)d_in[5];
  const float* b_ih   = (const float*)d_in[6];
  const float* b_hh   = (const float*)d_in[7];
  const float* fc_w   = (const float*)d_in[8];
  const float* fc_b   = (const float*)d_in[9];
  float* out = (float*)d_out;

  char* wsb = (char*)d_ws;
  size_t off = 0;
  auto alloc = [&](size_t bytes) {
    void* p = wsb + off;
    off = (off + bytes + 255) & ~(size_t)255;
    return p;
  };
  const int nblk = (N_NODES + 31) / 32;  // 1563
  int* deg      = (int*)alloc(sizeof(int) * T_DIM * N_NODES);
  int* row_ptr  = (int*)alloc(sizeof(int) * T_DIM * (N_NODES + 1));
  int* cursor   = (int*)alloc(sizeof(int) * T_DIM * N_NODES);
  int* csr      = (int*)alloc(sizeof(int) * (size_t)T_DIM * E_EDGES);
  unsigned short* s = (unsigned short*)alloc(sizeof(unsigned short) * (size_t)T_DIM * N_NODES * H_DIM);
  float* partials = (float*)alloc(sizeof(float) * (size_t)T_DIM * nblk * H_DIM);
  float* seq_raw  = (float*)alloc(sizeof(float) * T_DIM * H_DIM);
  float* gx       = (float*)alloc(sizeof(float) * T_DIM * 256);

  hipMemsetAsync(deg, 0, sizeof(int) * T_DIM * N_NODES, stream);

  int eblocks = (T_DIM * E_EDGES + 255) / 256;
  k_count<<<eblocks, 256, 0, stream>>>(ei, deg);
  k_scan<<<T_DIM, 1024, 0, stream>>>(deg, row_ptr, cursor);
  k_fill<<<eblocks, 256, 0, stream>>>(ei, cursor, csr);
  dim3 g4((N_NODES + 255) / 256, T_DIM);
  k_xw<<<g4, 256, 0, stream>>>(x, conv_w, deg, s);
  dim3 g5(nblk, T_DIM);
  k_gather<<<g5, 256, 0, stream>>>(s, csr, row_ptr, conv_b, partials, nblk);
  k_reduce<<<T_DIM, 256, 0, stream>>>(partials, seq_raw, nblk);
  k_gatex<<<T_DIM, 256, 0, stream>>>(seq_raw, w_ih, b_ih, b_hh, gx);
  k_lstm<<<1, 256, 0, stream>>>(gx, w_hh, fc_w, fc_b, out);
}

// Round 2
// 893.755 us; speedup vs baseline: 1.2438x; 1.2438x over previous
//
#include <hip/hip_runtime.h>
#include <hip/hip_bf16.h>
#include <cstdint>
#include <cstddef>

#define T_DIM 8
#define N_NODES 50000
#define F_DIM 64
#define H_DIM 32
#define L_DIM 64
#define E_EDGES 800000
#define RANGES 8
#define CHUNKS 32

__device__ __forceinline__ unsigned short f2bf(float f) {
  unsigned u = __float_as_uint(f);
  u = u + 0x7FFFu + ((u >> 16) & 1u);   // round-to-nearest-even
  return (unsigned short)(u >> 16);
}
__device__ __forceinline__ float bf2f(unsigned short b) {
  return __uint_as_float(((unsigned)b) << 16);
}

// K1: deg[t][dst] counts (self-loop added later as +1)
__global__ void k_count(const int* __restrict__ ei, int* __restrict__ deg) {
  int idx = blockIdx.x * 256 + threadIdx.x;
  if (idx >= T_DIM * E_EDGES) return;
  int t = idx / E_EDGES;
  int e = idx - t * E_EDGES;
  int dst = ei[(t * 2 + 1) * E_EDGES + e];
  atomicAdd(&deg[t * N_NODES + dst], 1);
}

// K2: per-t exclusive prefix sum of deg -> row_ptr, cursor (copy). 1024 threads/block, 1 block per t.
__global__ void k_scan(const int* __restrict__ deg, int* __restrict__ row_ptr,
                       int* __restrict__ cursor) {
  int t = blockIdx.x;
  const int* d = deg + t * N_NODES;
  int* rp = row_ptr + (size_t)t * (N_NODES + 1);
  int* cur = cursor + t * N_NODES;
  __shared__ int wsum[16];
  __shared__ int chunk_total_sh;
  int tid = threadIdx.x;
  int lane = tid & 63, wid = tid >> 6;
  int carry = 0;
  for (int base = 0; base < N_NODES; base += 4096) {
    int i0 = base + tid * 4;
    int v0 = (i0 + 0 < N_NODES) ? d[i0 + 0] : 0;
    int v1 = (i0 + 1 < N_NODES) ? d[i0 + 1] : 0;
    int v2 = (i0 + 2 < N_NODES) ? d[i0 + 2] : 0;
    int v3 = (i0 + 3 < N_NODES) ? d[i0 + 3] : 0;
    int tsum = v0 + v1 + v2 + v3;
    // inclusive wave scan of tsum
    int sc = tsum;
    #pragma unroll
    for (int off = 1; off < 64; off <<= 1) {
      int o = __shfl_up(sc, off, 64);
      if (lane >= off) sc += o;
    }
    if (lane == 63) wsum[wid] = sc;
    __syncthreads();
    if (wid == 0) {
      int wv = (lane < 16) ? wsum[lane] : 0;
      int ws = wv;
      #pragma unroll
      for (int off = 1; off < 16; off <<= 1) {
        int o = __shfl_up(ws, off, 64);
        if (lane >= off) ws += o;
      }
      if (lane < 16) wsum[lane] = ws - wv;  // exclusive wave offset
      if (lane == 15) chunk_total_sh = ws;
    }
    __syncthreads();
    int excl = carry + wsum[wid] + (sc - tsum);
    if (i0 + 0 < N_NODES) { rp[i0 + 0] = excl;                cur[i0 + 0] = excl; }
    if (i0 + 1 < N_NODES) { rp[i0 + 1] = excl + v0;           cur[i0 + 1] = excl + v0; }
    if (i0 + 2 < N_NODES) { rp[i0 + 2] = excl + v0 + v1;      cur[i0 + 2] = excl + v0 + v1; }
    if (i0 + 3 < N_NODES) { rp[i0 + 3] = excl + v0 + v1 + v2; cur[i0 + 3] = excl + v0 + v1 + v2; }
    carry += chunk_total_sh;
    __syncthreads();
  }
  if (tid == 0) rp[N_NODES] = carry;  // == E_EDGES
}

// K3: fill CSR column (src) lists, XCD-range partitioned.
// bid%8 = node-range -> pinned to one XCD by round-robin dispatch; that XCD's
// L2 keeps the 0.4MB-per-t csr slice resident so 4B scatter writes coalesce
// into full 64B lines before writeback (fixes 420MB HBM write amplification).
__global__ void k_fill(const int* __restrict__ ei, int* __restrict__ cursor,
                       int* __restrict__ csr) {
  int bid = blockIdx.x;
  int range = bid & (RANGES - 1);
  int rest = bid >> 3;
  int t = rest & (T_DIM - 1);
  int chunk = rest >> 3;                      // 0..CHUNKS-1
  const int eper = E_EDGES / CHUNKS;          // 25000
  int e0 = chunk * eper;
  int lo = range * (N_NODES / RANGES);
  int hi = lo + (N_NODES / RANGES);
  const int* srcp = ei + (size_t)(t * 2 + 0) * E_EDGES;
  const int4* dst4 = reinterpret_cast<const int4*>(ei + (size_t)(t * 2 + 1) * E_EDGES);
  int* cur = cursor + t * N_NODES;
  int* c = csr + (size_t)t * E_EDGES;
  const int q0 = e0 >> 2, q1 = (e0 + eper) >> 2;   // eper divisible by 4
  for (int q = q0 + threadIdx.x; q < q1; q += 256) {
    int4 d = dst4[q];
    int e = q << 2;
    #pragma unroll
    for (int k = 0; k < 4; ++k) {
      int dst = (k == 0) ? d.x : (k == 1) ? d.y : (k == 2) ? d.z : d.w;
      if (dst >= lo && dst < hi) {
        int pos = atomicAdd(&cur[dst], 1);
        c[pos] = srcp[e + k];
      }
    }
  }
}

// K4: s[t][n][:] = rsqrt(deg+1) * (x[t][n][:] @ conv_w), stored bf16
__global__ void k_xw(const float* __restrict__ x, const float* __restrict__ w,
                     const int* __restrict__ deg, unsigned short* __restrict__ s) {
  int t = blockIdx.y;
  int n = blockIdx.x * 256 + threadIdx.x;
  if (n >= N_NODES) return;
  const float4* xr = reinterpret_cast<const float4*>(x + ((size_t)t * N_NODES + n) * F_DIM);
  const float4* w4 = reinterpret_cast<const float4*>(w);
  float4 acc[8];
  #pragma unroll
  for (int h = 0; h < 8; ++h) acc[h] = make_float4(0.f, 0.f, 0.f, 0.f);
  for (int k4 = 0; k4 < 16; ++k4) {
    float4 xv = xr[k4];
    #pragma unroll
    for (int kk = 0; kk < 4; ++kk) {
      float xs = (kk == 0) ? xv.x : (kk == 1) ? xv.y : (kk == 2) ? xv.z : xv.w;
      #pragma unroll
      for (int h = 0; h < 8; ++h) {
        float4 wv = w4[(k4 * 4 + kk) * 8 + h];   // wave-uniform -> scalar loads
        acc[h].x += xs * wv.x; acc[h].y += xs * wv.y;
        acc[h].z += xs * wv.z; acc[h].w += xs * wv.w;
      }
    }
  }
  float dinv = rsqrtf((float)(deg[t * N_NODES + n] + 1));
  unsigned short* srow = s + ((size_t)t * N_NODES + n) * H_DIM;
  #pragma unroll
  for (int h = 0; h < 8; ++h) {
    uint2 u;
    u.x = (unsigned)f2bf(acc[h].x * dinv) | ((unsigned)f2bf(acc[h].y * dinv) << 16);
    u.y = (unsigned)f2bf(acc[h].z * dinv) | ((unsigned)f2bf(acc[h].w * dinv) << 16);
    *reinterpret_cast<uint2*>(srow + h * 4) = u;
  }
}

// K5: per-node gather of s[src] over incoming edges + self, relu(dinv*sum + b), block partial pool
__global__ void k_gather(const unsigned short* __restrict__ s, const int* __restrict__ csr,
                         const int* __restrict__ row_ptr, const float* __restrict__ conv_b,
                         float* __restrict__ partials, int nblk) {
  int t = blockIdx.y;
  int tid = threadIdx.x;
  int g = tid >> 3, j = tid & 7;   // 32 node-groups x 8 lanes; lane covers 4 of 32 features
  int n = blockIdx.x * 32 + g;
  float4 val = make_float4(0.f, 0.f, 0.f, 0.f);
  if (n < N_NODES) {
    const int* rp = row_ptr + (size_t)t * (N_NODES + 1) + n;
    int start = rp[0], end = rp[1];
    float dinv = rsqrtf((float)(end - start + 1));
    const unsigned short* sbase = s + (size_t)t * N_NODES * H_DIM;
    ushort4 u = *reinterpret_cast<const ushort4*>(sbase + (size_t)n * H_DIM + j * 4);
    float4 acc = make_float4(bf2f(u.x), bf2f(u.y), bf2f(u.z), bf2f(u.w));
    const int* col = csr + (size_t)t * E_EDGES;
    for (int p = start; p < end; ++p) {
      int c = col[p];
      ushort4 v = *reinterpret_cast<const ushort4*>(sbase + (size_t)c * H_DIM + j * 4);
      acc.x += bf2f(v.x); acc.y += bf2f(v.y); acc.z += bf2f(v.z); acc.w += bf2f(v.w);
    }
    const float4 b = reinterpret_cast<const float4*>(conv_b)[j];
    val.x = fmaxf(acc.x * dinv + b.x, 0.f);
    val.y = fmaxf(acc.y * dinv + b.y, 0.f);
    val.z = fmaxf(acc.z * dinv + b.z, 0.f);
    val.w = fmaxf(acc.w * dinv + b.w, 0.f);
  }
  // reduce across the 8 groups of each wave (classes = lane&7)
  #pragma unroll
  for (int off = 8; off < 64; off <<= 1) {
    val.x += __shfl_xor(val.x, off, 64);
    val.y += __shfl_xor(val.y, off, 64);
    val.z += __shfl_xor(val.z, off, 64);
    val.w += __shfl_xor(val.w, off, 64);
  }
  __shared__ float red[4][32];
  int wid = tid >> 6, lane = tid & 63;
  if (lane < 8) {
    red[wid][lane * 4 + 0] = val.x;
    red[wid][lane * 4 + 1] = val.y;
    red[wid][lane * 4 + 2] = val.z;
    red[wid][lane * 4 + 3] = val.w;
  }
  __syncthreads();
  if (tid < 32) {
    float sum = red[0][tid] + red[1][tid] + red[2][tid] + red[3][tid];
    partials[((size_t)t * nblk + blockIdx.x) * H_DIM + tid] = sum;
  }
}

// K5b: reduce per-block partials -> pooled node-sum per (t,h)
__global__ void k_reduce(const float* __restrict__ partials, float* __restrict__ seq_raw,
                         int nblk) {
  int t = blockIdx.x;
  int tid = threadIdx.x;           // 256
  int h = tid & 31, w = tid >> 5;  // 8 slices
  float sum = 0.f;
  for (int b = w; b < nblk; b += 8) sum += partials[((size_t)t * nblk + b) * H_DIM + h];
  __shared__ float red[8][32];
  red[w][h] = sum;
  __syncthreads();
  if (tid < 32) {
    float sm = 0.f;
    #pragma unroll
    for (int i = 0; i < 8; ++i) sm += red[i][tid];
    seq_raw[t * H_DIM + tid] = sm;
  }
}

// K6a: precompute per-t x-part of LSTM gates: gx[t][g] = b_ih+b_hh + w_ih[g,:]@(seq_sum/N)
__global__ void k_gatex(const float* __restrict__ seq_raw, const float* __restrict__ w_ih,
                        const float* __restrict__ b_ih, const float* __restrict__ b_hh,
                        float* __restrict__ gx) {
  int t = blockIdx.x;
  int j = threadIdx.x;  // 256
  __shared__ float xb[32];
  if (j < 32) xb[j] = seq_raw[t * H_DIM + j] * (1.0f / (float)N_NODES);
  __syncthreads();
  float g = b_ih[j] + b_hh[j];
  #pragma unroll
  for (int k = 0; k < 32; ++k) g += w_ih[j * 32 + k] * xb[k];
  gx[t * 256 + j] = g;
}

// K6b: sequential LSTM (8 steps) + fc head. Single block.
__global__ void k_lstm(const float* __restrict__ gx, const float* __restrict__ w_hh,
                       const float* __restrict__ fc_w, const float* __restrict__ fc_b,
                       float* __restrict__ out) {
  __shared__ float hbuf[64], cbuf[64], gates[256];
  int j = threadIdx.x;  // 256
  if (j < 64) { hbuf[j] = 0.f; cbuf[j] = 0.f; }
  __syncthreads();
  for (int t = 0; t < T_DIM; ++t) {
    float g = gx[t * 256 + j];
    #pragma unroll 8
    for (int k = 0; k < 64; ++k) g += w_hh[j * 64 + k] * hbuf[k];
    gates[j] = g;
    __syncthreads();
    if (j < 64) {
      float ii = 1.f / (1.f + expf(-gates[j]));
      float ff = 1.f / (1.f + expf(-gates[64 + j]));
      float gg = tanhf(gates[128 + j]);
      float oo = 1.f / (1.f + expf(-gates[192 + j]));
      float c = ff * cbuf[j] + ii * gg;
      cbuf[j] = c;
      hbuf[j] = oo * tanhf(c);
    }
    __syncthreads();
  }
  if (j == 0) {
    float acc = 0.f;
    for (int k = 0; k < 64; ++k) acc += hbuf[k] * fc_w[k];
    out[0] = acc + fc_b[0];
  }
}

extern "C" void kernel_launch(void* const* d_in, const int* in_sizes, int n_in,
                              void* d_out, int out_size, void* d_ws, size_t ws_size,
                              hipStream_t stream) {
  const float* x      = (const float*)d_in[0];
  const int*   ei     = (const int*)  d_in[1];
  const float* conv_w = (const float*)d_in[2];
  const float* conv_b = (const float*)d_in[3];
  const float* w_ih   = (const float*)d_in[4];
  const float* w_hh   = (const float*)d_in[5];
  const float* b_ih   = (const float*)d_in[6];
  const float* b_hh   = (const float*)d_in[7];
  const float* fc_w   = (const float*)d_in[8];
  const float* fc_b   = (const float*)d_in[9];
  float* out = (float*)d_out;

  char* wsb = (char*)d_ws;
  size_t off = 0;
  auto alloc = [&](size_t bytes) {
    void* p = wsb + off;
    off = (off + bytes + 255) & ~(size_t)255;
    return p;
  };
  const int nblk = (N_NODES + 31) / 32;  // 1563
  int* deg      = (int*)alloc(sizeof(int) * T_DIM * N_NODES);
  int* row_ptr  = (int*)alloc(sizeof(int) * T_DIM * (N_NODES + 1));
  int* cursor   = (int*)alloc(sizeof(int) * T_DIM * N_NODES);
  int* csr      = (int*)alloc(sizeof(int) * (size_t)T_DIM * E_EDGES);
  unsigned short* s = (unsigned short*)alloc(sizeof(unsigned short) * (size_t)T_DIM * N_NODES * H_DIM);
  float* partials = (float*)alloc(sizeof(float) * (size_t)T_DIM * nblk * H_DIM);
  float* seq_raw  = (float*)alloc(sizeof(float) * T_DIM * H_DIM);
  float* gx       = (float*)alloc(sizeof(float) * T_DIM * 256);

  hipMemsetAsync(deg, 0, sizeof(int) * T_DIM * N_NODES, stream);

  int eblocks = (T_DIM * E_EDGES + 255) / 256;
  k_count<<<eblocks, 256, 0, stream>>>(ei, deg);
  k_scan<<<T_DIM, 1024, 0, stream>>>(deg, row_ptr, cursor);
  k_fill<<<RANGES * T_DIM * CHUNKS, 256, 0, stream>>>(ei, cursor, csr);
  dim3 g4((N_NODES + 255) / 256, T_DIM);
  k_xw<<<g4, 256, 0, stream>>>(x, conv_w, deg, s);
  dim3 g5(nblk, T_DIM);
  k_gather<<<g5, 256, 0, stream>>>(s, csr, row_ptr, conv_b, partials, nblk);
  k_reduce<<<T_DIM, 256, 0, stream>>>(partials, seq_raw, nblk);
  k_gatex<<<T_DIM, 256, 0, stream>>>(seq_raw, w_ih, b_ih, b_hh, gx);
  k_lstm<<<1, 256, 0, stream>>>(gx, w_hh, fc_w, fc_b, out);
}